// Round 1
// baseline (786.500 us; speedup 1.0000x reference)
//
#include <hip/hip_runtime.h>
#include <math.h>

// Problem constants
#define B   32
#define Q   1024
#define CC  256
#define HD  2
#define SCALE 0.0625f   // C^-0.5 = 1/16

// ---------------- workspace layout (in floats) ----------------
// Pt      : [HD][B][256 d][1024 r]  (P transposed, P = M @ (U*SCALE))
// rmax_all: [HD*B][1024]
// rmax_hi : [HD*B][1024]   (max over j>=512 only)
// pcolmax : [HD*B][8 rowblocks][1024]
// pmin    : [512]  (per k-gemm block raw min)
// m0      : [1]    (raw global min of head-0 K)
// alpha   : [HD*B][1024]
#define PT_OFF   ((size_t)0)
#define PT_SZ    ((size_t)HD*B*CC*Q)        // 16,777,216
#define RMA_OFF  (PT_OFF + PT_SZ)
#define RM_SZ    ((size_t)HD*B*Q)           // 65,536
#define RMH_OFF  (RMA_OFF + RM_SZ)
#define PCM_OFF  (RMH_OFF + RM_SZ)
#define PCM_SZ   ((size_t)HD*B*8*Q)         // 524,288
#define PMIN_OFF (PCM_OFF + PCM_SZ)
#define M0_OFF   (PMIN_OFF + 512)
#define AL_OFF   (M0_OFF + 4)
// total ~17.5M floats = ~70 MB

// Fully-converged Newton solve of y^3/3 + y = x  (== nonsat_activation limit).
// Strictly monotone in x, so it commutes with max/min (applied post-reduction).
__device__ __forceinline__ float nonsat(float x) {
    float y = x;
#pragma unroll
    for (int i = 0; i < 24; ++i) {
        float y2 = y * y;
        y = fmaf(0.66666667f * y, y2, x) / (y2 + 1.0f);
    }
    return y;
}

// Virtual M row fetch: rows 0..511 = x1[b], rows 512..1023 = x2[b] padded to 256 ch.
__device__ __forceinline__ float m_elem(const float* __restrict__ x1,
                                        const float* __restrict__ x2,
                                        int b, int row, int col) {
    if (row < 512) return x1[((size_t)b * 512 + row) * 256 + col];
    return (col < 192) ? x2[((size_t)b * 512 + (row - 512)) * 192 + col] : 0.0f;
}

// ---------------------------------------------------------------------------
// Kernel 1: Pt[h][b][d][r] = sum_c M[b][r][c] * U[h][c][d] * SCALE
// Block tile 128r x 128d, thread tile 8x8, k-chunk 32.
// grid = (h*32+b)*16 + (rt*2 + dt), 1024 blocks x 256 threads.
// ---------------------------------------------------------------------------
__global__ __launch_bounds__(256, 2)
void k_gemm_p(const float* __restrict__ x1, const float* __restrict__ x2,
              const float* __restrict__ U, float* __restrict__ pt) {
    __shared__ __align__(16) float Al[32 * 132]; // M^T chunk: [cc][rr], stride 132
    __shared__ __align__(16) float Bl[32 * 128]; // U chunk:   [cc][dd], stride 128

    const int blk  = blockIdx.x;
    const int tile = blk & 15;
    const int hb   = blk >> 4;
    const int b    = hb & 31;
    const int h    = hb >> 5;
    const int rt   = tile >> 1;
    const int dt   = tile & 1;
    const int r0   = rt * 128;
    const int d0   = dt * 128;
    const int t    = threadIdx.x;
    const int rr0  = (t & 15) * 4;
    const int dd0  = (t >> 4) * 4;

    float acc[8][8];
#pragma unroll
    for (int i = 0; i < 8; ++i)
#pragma unroll
        for (int j = 0; j < 8; ++j) acc[i][j] = 0.0f;

    for (int kc = 0; kc < 8; ++kc) {
        const int c0 = kc * 32;
        __syncthreads();
        { // stage A: M[b][r0..+128][c0..+32] transposed -> Al[cc*132 + rr]
            const int cc = t & 31, rb8 = t >> 5;
            const int col = c0 + cc;
#pragma unroll
            for (int p = 0; p < 16; ++p) {
                const int rr = p * 8 + rb8;
                Al[cc * 132 + rr] = m_elem(x1, x2, b, r0 + rr, col);
            }
        }
        { // stage B: U[h][c0..+32][d0..+128] * SCALE -> Bl[cc*128 + dd]
            const int dd = t & 127, cb = t >> 7;
#pragma unroll
            for (int p = 0; p < 16; ++p) {
                const int cc = p * 2 + cb;
                Bl[cc * 128 + dd] =
                    U[((size_t)h * 256 + c0 + cc) * 256 + d0 + dd] * SCALE;
            }
        }
        __syncthreads();
#pragma unroll 8
        for (int c = 0; c < 32; ++c) {
            float4 a0 = *(const float4*)&Al[c * 132 + rr0];
            float4 a1 = *(const float4*)&Al[c * 132 + rr0 + 64];
            float4 b0 = *(const float4*)&Bl[c * 128 + dd0];
            float4 b1 = *(const float4*)&Bl[c * 128 + dd0 + 64];
            float av[8] = {a0.x, a0.y, a0.z, a0.w, a1.x, a1.y, a1.z, a1.w};
            float bv[8] = {b0.x, b0.y, b0.z, b0.w, b1.x, b1.y, b1.z, b1.w};
#pragma unroll
            for (int i = 0; i < 8; ++i)
#pragma unroll
                for (int j = 0; j < 8; ++j)
                    acc[i][j] = fmaf(av[i], bv[j], acc[i][j]);
        }
    }

    // store transposed: Pt[hb][d][r]
    float* ptb = pt + (size_t)hb * CC * Q;
#pragma unroll
    for (int j = 0; j < 8; ++j) {
        const int dloc = d0 + dd0 + (j & 3) + (j >> 2) * 64;
        float4 v0 = make_float4(acc[0][j], acc[1][j], acc[2][j], acc[3][j]);
        float4 v1 = make_float4(acc[4][j], acc[5][j], acc[6][j], acc[7][j]);
        *(float4*)&ptb[(size_t)dloc * Q + r0 + rr0]      = v0;
        *(float4*)&ptb[(size_t)dloc * Q + r0 + rr0 + 64] = v1;
    }
}

// ---------------------------------------------------------------------------
// Kernel 2: K[r][j] = sum_d Pt[d][r] * M[j][d]; never stored — reduced on the
// fly to rowmax_all / rowmax_hi (j>=512), per-rowblock colmax, and raw min.
// Block = (h,b,rb of 128 rows), loops all 8 j-tiles of 128. grid 512 x 256.
// ---------------------------------------------------------------------------
__global__ __launch_bounds__(256, 2)
void k_gemm_k(const float* __restrict__ x1, const float* __restrict__ x2,
              const float* __restrict__ pt, float* __restrict__ rmax_all,
              float* __restrict__ rmax_hi, float* __restrict__ pcolmax,
              float* __restrict__ pmin) {
    __shared__ __align__(16) float Al[32 * 128]; // Pt chunk: [dd][rr], stride 128
    __shared__ __align__(16) float Bl[32 * 132]; // M^T chunk: [dd][jj], stride 132
    __shared__ float red[256];

    const int blk = blockIdx.x;
    const int rb  = blk & 7;
    const int hb  = blk >> 3;  // h*32+b ; head = hb>>5
    const int b   = hb & 31;
    const int t   = threadIdx.x;
    const int r0  = rb * 128;
    const int rr0 = (t & 15) * 4;
    const int jj0 = (t >> 4) * 4;

    const float* ptb = pt + (size_t)hb * CC * Q;

    float rA[8], rH[8];
#pragma unroll
    for (int i = 0; i < 8; ++i) { rA[i] = -INFINITY; rH[i] = -INFINITY; }
    float gmin = INFINITY;

    for (int jt = 0; jt < 8; ++jt) {
        const int j0 = jt * 128;
        float acc[8][8];
#pragma unroll
        for (int i = 0; i < 8; ++i)
#pragma unroll
            for (int j = 0; j < 8; ++j) acc[i][j] = 0.0f;

        for (int kc = 0; kc < 8; ++kc) {
            const int d0 = kc * 32;
            __syncthreads();
            { // stage A: Pt[d0..+32][r0..+128] -> Al[dd*128 + rr]
                const int rr = t & 127, db = t >> 7;
#pragma unroll
                for (int p = 0; p < 16; ++p) {
                    const int dd = p * 2 + db;
                    Al[dd * 128 + rr] = ptb[(size_t)(d0 + dd) * Q + r0 + rr];
                }
            }
            { // stage B: M[b][j0..+128][d0..+32] transposed -> Bl[dd*132 + jj]
                const int dd = t & 31, jb8 = t >> 5;
                const int dcol = d0 + dd;
#pragma unroll
                for (int p = 0; p < 16; ++p) {
                    const int jj = p * 8 + jb8;
                    Bl[dd * 132 + jj] = m_elem(x1, x2, b, j0 + jj, dcol);
                }
            }
            __syncthreads();
#pragma unroll 8
            for (int c = 0; c < 32; ++c) {
                float4 a0 = *(const float4*)&Al[c * 128 + rr0];
                float4 a1 = *(const float4*)&Al[c * 128 + rr0 + 64];
                float4 b0 = *(const float4*)&Bl[c * 132 + jj0];
                float4 b1 = *(const float4*)&Bl[c * 132 + jj0 + 64];
                float av[8] = {a0.x, a0.y, a0.z, a0.w, a1.x, a1.y, a1.z, a1.w};
                float bv[8] = {b0.x, b0.y, b0.z, b0.w, b1.x, b1.y, b1.z, b1.w};
#pragma unroll
                for (int i = 0; i < 8; ++i)
#pragma unroll
                    for (int j = 0; j < 8; ++j)
                        acc[i][j] = fmaf(av[i], bv[j], acc[i][j]);
            }
        }

        // j-tile epilogue: reductions. j>=512 <=> jt>=4 (clean split).
        const bool hi = (jt >= 4);
#pragma unroll
        for (int i = 0; i < 8; ++i) {
            float m = acc[i][0];
#pragma unroll
            for (int j = 1; j < 8; ++j) m = fmaxf(m, acc[i][j]);
            rA[i] = fmaxf(rA[i], m);
            if (hi) rH[i] = fmaxf(rH[i], m);
#pragma unroll
            for (int j = 0; j < 8; ++j) gmin = fminf(gmin, acc[i][j]);
        }
        // partial colmax over this block's 128 rows: reduce across the 16
        // lanes sharing jj0 (consecutive lanes t&15=0..15, same t>>4).
#pragma unroll
        for (int j = 0; j < 8; ++j) {
            float m = acc[0][j];
#pragma unroll
            for (int i = 1; i < 8; ++i) m = fmaxf(m, acc[i][j]);
            m = fmaxf(m, __shfl_xor(m, 1));
            m = fmaxf(m, __shfl_xor(m, 2));
            m = fmaxf(m, __shfl_xor(m, 4));
            m = fmaxf(m, __shfl_xor(m, 8));
            if ((t & 15) == 0) {
                const int jloc = jj0 + (j & 3) + (j >> 2) * 64;
                pcolmax[((size_t)hb * 8 + rb) * Q + j0 + jloc] = m;
            }
        }
    }

    // rowmax reduce across the 16 threads (t>>4 = 0..15) sharing each row set
#pragma unroll 1
    for (int i = 0; i < 8; ++i) {
        __syncthreads();
        red[t] = rA[i];
        __syncthreads();
        if (t < 16) {
            float m = red[t];
            for (int g = 1; g < 16; ++g) m = fmaxf(m, red[t + g * 16]);
            const int row = t * 4 + (i & 3) + (i >> 2) * 64;
            rmax_all[(size_t)hb * Q + r0 + row] = m;
        }
        __syncthreads();
        red[t] = rH[i];
        __syncthreads();
        if (t < 16) {
            float m = red[t];
            for (int g = 1; g < 16; ++g) m = fmaxf(m, red[t + g * 16]);
            const int row = t * 4 + (i & 3) + (i >> 2) * 64;
            rmax_hi[(size_t)hb * Q + r0 + row] = m;
        }
    }

    // block raw-min
#pragma unroll
    for (int off = 1; off < 64; off <<= 1) gmin = fminf(gmin, __shfl_xor(gmin, off));
    __syncthreads();
    if ((t & 63) == 0) red[t >> 6] = gmin;
    __syncthreads();
    if (t == 0)
        pmin[blockIdx.x] = fminf(fminf(red[0], red[1]), fminf(red[2], red[3]));
}

// Reduce raw min over head-0's 256 blocks (blockIdx 0..255 of k_gemm_k).
__global__ void k_min(const float* __restrict__ pmin, float* __restrict__ m0) {
    __shared__ float s[4];
    const int t = threadIdx.x;
    float v = pmin[t];
#pragma unroll
    for (int off = 1; off < 64; off <<= 1) v = fminf(v, __shfl_xor(v, off));
    if ((t & 63) == 0) s[t >> 6] = v;
    __syncthreads();
    if (t == 0) m0[0] = fminf(fminf(s[0], s[1]), fminf(s[2], s[3]));
}

// alpha[hb][i] = act(rows_raw) + act(cols_raw), with m0 clipping for i<512
// (activation commutes with max; m0 applied pre-activation).
__global__ void k_alpha(const float* __restrict__ rmax_all,
                        const float* __restrict__ rmax_hi,
                        const float* __restrict__ pcolmax,
                        const float* __restrict__ m0p,
                        float* __restrict__ alpha) {
    const int hb = blockIdx.x; // 0..63
    const float m0 = m0p[0];
    for (int it = 0; it < 4; ++it) {
        const int i = it * 256 + threadIdx.x;
        const float rraw = (i < 512) ? fmaxf(m0, rmax_hi[(size_t)hb * Q + i])
                                     : rmax_all[(size_t)hb * Q + i];
        float call = -INFINITY, chi = -INFINITY;
#pragma unroll
        for (int rb = 0; rb < 8; ++rb) {
            const float v = pcolmax[((size_t)hb * 8 + rb) * Q + i];
            call = fmaxf(call, v);
            if (rb >= 4) chi = fmaxf(chi, v);
        }
        const float craw = (i < 512) ? fmaxf(m0, chi) : call;
        alpha[(size_t)hb * Q + i] = nonsat(rraw) + nonsat(craw);
    }
}

// Softmax over each 512-segment of alpha, then r_c = sum_l w_l * ctx[b][l][c].
// block = hb*2 + seg, 128 blocks x 256 threads. Context 1 channels >=192 are 0.
__global__ __launch_bounds__(256)
void k_out(const float* __restrict__ alpha, const float* __restrict__ x1,
           const float* __restrict__ x2, float* __restrict__ out) {
    __shared__ float w[512];
    __shared__ float sm[4], ss[4];
    const int blk = blockIdx.x;
    const int seg = blk & 1;
    const int hb  = blk >> 1;
    const int b   = hb & 31;
    const int t   = threadIdx.x;
    const float* ap = alpha + (size_t)hb * Q + seg * 512;
    const float a0 = ap[t], a1 = ap[t + 256];

    float m = fmaxf(a0, a1);
#pragma unroll
    for (int off = 1; off < 64; off <<= 1) m = fmaxf(m, __shfl_xor(m, off));
    if ((t & 63) == 0) sm[t >> 6] = m;
    __syncthreads();
    const float amax = fmaxf(fmaxf(sm[0], sm[1]), fmaxf(sm[2], sm[3]));

    const float e0 = __expf(a0 - amax), e1 = __expf(a1 - amax);
    w[t] = e0; w[t + 256] = e1;
    float s = e0 + e1;
#pragma unroll
    for (int off = 1; off < 64; off <<= 1) s += __shfl_xor(s, off);
    if ((t & 63) == 0) ss[t >> 6] = s;
    __syncthreads();   // also guarantees all w[] writes visible
    const float inv = 1.0f / (ss[0] + ss[1] + ss[2] + ss[3]);

    float acc = 0.0f;
    if (seg == 0) {
        const float* xp = x1 + (size_t)b * 512 * 256 + t;
#pragma unroll 4
        for (int l = 0; l < 512; ++l) acc = fmaf(w[l], xp[(size_t)l * 256], acc);
        out[blk * 256 + t] = acc * inv;
    } else {
        if (t < 192) {
            const float* xp = x2 + (size_t)b * 512 * 192 + t;
#pragma unroll 4
            for (int l = 0; l < 512; ++l) acc = fmaf(w[l], xp[(size_t)l * 192], acc);
            out[blk * 256 + t] = acc * inv;
        } else {
            out[blk * 256 + t] = 0.0f;  // padded channels: exact zero
        }
    }
}

extern "C" void kernel_launch(void* const* d_in, const int* in_sizes, int n_in,
                              void* d_out, int out_size, void* d_ws, size_t ws_size,
                              hipStream_t stream) {
    const float* x1 = (const float*)d_in[0];
    const float* x2 = (const float*)d_in[1];
    const float* U  = (const float*)d_in[2];
    float* out = (float*)d_out;
    float* ws  = (float*)d_ws;

    float* pt   = ws + PT_OFF;
    float* rma  = ws + RMA_OFF;
    float* rmh  = ws + RMH_OFF;
    float* pcm  = ws + PCM_OFF;
    float* pmin = ws + PMIN_OFF;
    float* m0   = ws + M0_OFF;
    float* al   = ws + AL_OFF;

    hipLaunchKernelGGL(k_gemm_p, dim3(1024), dim3(256), 0, stream, x1, x2, U, pt);
    hipLaunchKernelGGL(k_gemm_k, dim3(512),  dim3(256), 0, stream, x1, x2, pt,
                       rma, rmh, pcm, pmin);
    hipLaunchKernelGGL(k_min,    dim3(1),    dim3(256), 0, stream, pmin, m0);
    hipLaunchKernelGGL(k_alpha,  dim3(64),   dim3(256), 0, stream, rma, rmh, pcm, m0, al);
    hipLaunchKernelGGL(k_out,    dim3(128),  dim3(256), 0, stream, al, x1, x2, out);
}

// Round 2
// 315.420 us; speedup vs baseline: 2.4935x; 2.4935x over previous
//
#include <hip/hip_runtime.h>
#include <math.h>

typedef _Float16 h16;
typedef h16  h16x8 __attribute__((ext_vector_type(8)));
typedef h16  h16x4 __attribute__((ext_vector_type(4)));
typedef float f32x4 __attribute__((ext_vector_type(4)));

// ---------------- workspace layout (bytes) ----------------
// MH/ML : fp16 split of M [32 b][1024 j][256 d] (x2 zero-padded to 256)
// UHt/ULt: fp16 split of (U^T * 4) [2 h][256 d][256 c]
// rmax_all/rmax_hi: [64 hb][1024] f32 ; pcm: [64 hb][16 rb][1024] f32
// pmin: [1024] f32 ; m0: f32 ; alpha: [64 hb][1024] f32
#define MH_OFF   ((size_t)0)
#define ML_OFF   (MH_OFF + 16777216)
#define UHT_OFF  (ML_OFF + 16777216)
#define ULT_OFF  (UHT_OFF + 262144)
#define RMA_OFF  (ULT_OFF + 262144)
#define RMH_OFF  (RMA_OFF + 262144)
#define PCM_OFF  (RMH_OFF + 262144)
#define PMIN_OFF (PCM_OFF + 4194304)
#define M0_OFF   (PMIN_OFF + 4096)
#define AL_OFF   (M0_OFF + 16)
// total ~38.8 MB (fits the >=70 MB ws proven in R1)

// async global->LDS, 16B per lane; LDS dest = wave-uniform base + lane*16
__device__ __forceinline__ void glds16(const void* g, void* l) {
    __builtin_amdgcn_global_load_lds(
        (const __attribute__((address_space(1))) unsigned int*)g,
        (__attribute__((address_space(3))) unsigned int*)l, 16, 0, 0);
}

// Fully-converged Newton solve of y^3/3 + y = x (nonsat_activation limit).
// Strictly monotone -> commutes with max/min (applied post-reduction).
__device__ __forceinline__ float nonsat(float x) {
    float y = x;
#pragma unroll
    for (int i = 0; i < 24; ++i) {
        float y2 = y * y;
        y = fmaf(0.66666667f * y, y2, x) / (y2 + 1.0f);
    }
    return y;
}

// ---------------------------------------------------------------------------
// k_prep: build MH/ML (fp16 split of virtual M, x2 padded) and UHt/ULt
// (fp16 split of U^T * 4; the *4 = SCALE(1/16) * 64 P-prescale).
// ---------------------------------------------------------------------------
__global__ void k_prep(const float* __restrict__ x1, const float* __restrict__ x2,
                       const float* __restrict__ U, h16* __restrict__ MH,
                       h16* __restrict__ ML, h16* __restrict__ UHt,
                       h16* __restrict__ ULt) {
    const int gid = blockIdx.x * 256 + threadIdx.x;
    if (blockIdx.x < 8192) {
        const int g  = gid;              // (b, j, d4): 32*1024*64 groups
        const int d4 = (g & 63) * 4;
        const int j  = (g >> 6) & 1023;
        const int b  = g >> 16;
        float v[4];
        if (j < 512) {
            const float* p = x1 + ((size_t)(b * 512 + j) * 256 + d4);
#pragma unroll
            for (int k = 0; k < 4; ++k) v[k] = p[k];
        } else {
            const float* p = x2 + (size_t)(b * 512 + (j - 512)) * 192;
#pragma unroll
            for (int k = 0; k < 4; ++k) {
                const int c = d4 + k;
                v[k] = (c < 192) ? p[c] : 0.0f;
            }
        }
        h16x4 hh, ll;
#pragma unroll
        for (int k = 0; k < 4; ++k) {
            const h16 hi = (h16)v[k];
            hh[k] = hi;
            ll[k] = (h16)(v[k] - (float)hi);
        }
        const size_t o = (size_t)g * 4;
        *(h16x4*)&MH[o] = hh;
        *(h16x4*)&ML[o] = ll;
    } else {
        const int g = gid - 8192 * 256;  // 2*256*64 groups
        if (g < 32768) {
            const int c4 = (g & 63) * 4;
            const int d  = (g >> 6) & 255;
            const int h  = g >> 14;
            h16x4 hh, ll;
#pragma unroll
            for (int k = 0; k < 4; ++k) {
                const float v = U[((size_t)h * 256 + c4 + k) * 256 + d] * 4.0f;
                const h16 hi = (h16)v;
                hh[k] = hi;
                ll[k] = (h16)(v - (float)hi);
            }
            const size_t o = ((size_t)h * 256 + d) * 256 + c4;
            *(h16x4*)&UHt[o] = hh;
            *(h16x4*)&ULt[o] = ll;
        }
    }
}

// ---------------------------------------------------------------------------
// k_main: block = (hb, 64-row slice). Phase A: MFMA-compute P'[64][256]
// (= M @ U*4) and split to fp16 hi/lo in LDS. Phase B: K' = P'.M^T via
// 3-term split MFMA, reduced on the fly (rowmax all/hi, colmax, min).
// True K = K' * 2^-6.
// ---------------------------------------------------------------------------
__global__ __launch_bounds__(256, 2)
void k_main(const h16* __restrict__ MH, const h16* __restrict__ ML,
            const h16* __restrict__ UHt, const h16* __restrict__ ULt,
            float* __restrict__ rmax_all, float* __restrict__ rmax_hi,
            float* __restrict__ pcm, float* __restrict__ pmin) {
    __shared__ __align__(16) h16 sP[2][64 * 256];  // P hi/lo, [r][d] XOR-swizzled, 64 KB
    __shared__ __align__(16) h16 sB[256 * 32];     // staging tile, 16 KB

    const int blk  = blockIdx.x;       // 1024
    const int rblk = blk & 15;
    const int hb   = blk >> 4;
    const int b    = hb & 31;
    const int h    = hb >> 5;
    const int r0   = rblk * 64;
    const int t    = threadIdx.x;
    const int w    = t >> 6;           // wave 0..3
    const int l    = t & 63;
    const int q    = l >> 4;           // quad
    const int ln   = l & 15;
    const int lrow = l >> 2;           // staging: row within 16
    const int lcol = (l & 3) * 8;      // staging: col offset (halves)

    // ---------------- Phase A ----------------
    {
        h16* sA = (h16*)sP;            // 64x32 A-tile aliases sP (dead until epilogue)
        f32x4 acc[4][4];
        const f32x4 z4 = {0.f, 0.f, 0.f, 0.f};
#pragma unroll
        for (int i = 0; i < 4; ++i)
#pragma unroll
            for (int j = 0; j < 4; ++j) acc[i][j] = z4;

        for (int ch = 0; ch < 24; ++ch) {
            const int term = ch >> 3;                    // 0: MH*UH, 1: ML*UH, 2: MH*UL
            const int c0   = (ch & 7) * 32;
            const h16* As = (term == 1) ? ML : MH;
            const h16* Bs = (term == 2) ? ULt : UHt;
            __syncthreads();
            glds16(As + ((size_t)(b * 1024 + r0 + w * 16 + lrow) * 256 + c0 + lcol),
                   &sA[(w * 16) * 32]);
#pragma unroll
            for (int p = 0; p < 4; ++p)
                glds16(Bs + ((size_t)(h * 256 + w * 64 + p * 16 + lrow) * 256 + c0 + lcol),
                       &sB[(w * 64 + p * 16) * 32]);
            __syncthreads();
            h16x8 af[4], bf[4];
#pragma unroll
            for (int ti = 0; ti < 4; ++ti)
                af[ti] = *(const h16x8*)&sA[(ti * 16 + ln) * 32 + q * 8];
#pragma unroll
            for (int tj = 0; tj < 4; ++tj)
                bf[tj] = *(const h16x8*)&sB[(w * 64 + tj * 16 + ln) * 32 + q * 8];
#pragma unroll
            for (int ti = 0; ti < 4; ++ti)
#pragma unroll
                for (int tj = 0; tj < 4; ++tj)
                    acc[ti][tj] = __builtin_amdgcn_mfma_f32_16x16x32_f16(
                        af[ti], bf[tj], acc[ti][tj], 0, 0, 0);
        }
        __syncthreads();
        // split-store P' into sP, granule-swizzled: gran' = gran ^ (r&7)
#pragma unroll
        for (int ti = 0; ti < 4; ++ti)
#pragma unroll
            for (int tj = 0; tj < 4; ++tj)
#pragma unroll
                for (int reg = 0; reg < 4; ++reg) {
                    const int r = ti * 16 + q * 4 + reg;      // C/D: row=(q*4+reg)
                    const int d = w * 64 + tj * 16 + ln;      //      col=ln
                    const float v = acc[ti][tj][reg];
                    const h16 hi = (h16)v;
                    const h16 lo = (h16)(v - (float)hi);
                    const int off = r * 256 + (((d >> 3) ^ (r & 7)) << 3) + (d & 7);
                    sP[0][off] = hi;
                    sP[1][off] = lo;
                }
    }
    __syncthreads();

    // ---------------- Phase B ----------------
    float rA[16], rH[16];
#pragma unroll
    for (int i = 0; i < 16; ++i) { rA[i] = -INFINITY; rH[i] = -INFINITY; }
    float gmin = INFINITY;

    for (int jt = 0; jt < 4; ++jt) {
        const int j0 = jt * 256;
        f32x4 acc[4][4];
        const f32x4 z4 = {0.f, 0.f, 0.f, 0.f};
#pragma unroll
        for (int i = 0; i < 4; ++i)
#pragma unroll
            for (int j = 0; j < 4; ++j) acc[i][j] = z4;

        for (int ch = 0; ch < 24; ++ch) {
            const int term = ch >> 3;                 // 0: PH*MH, 1: PL*MH, 2: PH*ML
            const int kc   = ch & 7;
            const int d0   = kc * 32;
            const h16* Bs  = (term == 2) ? ML : MH;
            const h16* sPs = (term == 1) ? sP[1] : sP[0];
            __syncthreads();
#pragma unroll
            for (int p = 0; p < 4; ++p)
                glds16(Bs + ((size_t)(b * 1024 + j0 + w * 64 + p * 16 + lrow) * 256 + d0 + lcol),
                       &sB[(w * 64 + p * 16) * 32]);
            __syncthreads();
            h16x8 af[4], bf[4];
#pragma unroll
            for (int ti = 0; ti < 4; ++ti) {
                const int r = ti * 16 + ln;
                const int g = (kc * 4 + q) ^ (r & 7);
                af[ti] = *(const h16x8*)&sPs[r * 256 + g * 8];
            }
#pragma unroll
            for (int tj = 0; tj < 4; ++tj)
                bf[tj] = *(const h16x8*)&sB[(w * 64 + tj * 16 + ln) * 32 + q * 8];
#pragma unroll
            for (int ti = 0; ti < 4; ++ti)
#pragma unroll
                for (int tj = 0; tj < 4; ++tj)
                    acc[ti][tj] = __builtin_amdgcn_mfma_f32_16x16x32_f16(
                        af[ti], bf[tj], acc[ti][tj], 0, 0, 0);
        }

        // per-jt reductions. j>=512 <=> jt>=2.
        const bool hij = (jt >= 2);
#pragma unroll
        for (int ti = 0; ti < 4; ++ti)
#pragma unroll
            for (int reg = 0; reg < 4; ++reg) {
                float m = acc[ti][0][reg];
                m = fmaxf(m, acc[ti][1][reg]);
                m = fmaxf(m, acc[ti][2][reg]);
                m = fmaxf(m, acc[ti][3][reg]);
                const int idx = ti * 4 + reg;
                rA[idx] = fmaxf(rA[idx], m);
                if (hij) rH[idx] = fmaxf(rH[idx], m);
            }
#pragma unroll
        for (int ti = 0; ti < 4; ++ti)
#pragma unroll
            for (int tj = 0; tj < 4; ++tj)
#pragma unroll
                for (int reg = 0; reg < 4; ++reg)
                    gmin = fminf(gmin, acc[ti][tj][reg]);
        // colmax over this block's 64 rows: lane covers rows for its q;
        // combine quads via xor 16/32, q==0 lanes write.
#pragma unroll
        for (int tj = 0; tj < 4; ++tj) {
            float m = -INFINITY;
#pragma unroll
            for (int ti = 0; ti < 4; ++ti)
#pragma unroll
                for (int reg = 0; reg < 4; ++reg) m = fmaxf(m, acc[ti][tj][reg]);
            m = fmaxf(m, __shfl_xor(m, 16));
            m = fmaxf(m, __shfl_xor(m, 32));
            if (q == 0)
                pcm[(size_t)(hb * 16 + rblk) * 1024 + j0 + w * 64 + tj * 16 + ln] =
                    m * 0.015625f;
        }
    }

    // final cross-lane / cross-wave reductions (reuse sB as f32 scratch)
#pragma unroll
    for (int off = 1; off < 64; off <<= 1) gmin = fminf(gmin, __shfl_xor(gmin, off));

    __syncthreads();
    float* red = (float*)sB;   // [0..255]=all, [256..511]=hi, [512..515]=gmin
#pragma unroll
    for (int ti = 0; ti < 4; ++ti)
#pragma unroll
        for (int reg = 0; reg < 4; ++reg) {
            const int idx = ti * 4 + reg;
            float a = rA[idx], hh = rH[idx];
#pragma unroll
            for (int o2 = 1; o2 < 16; o2 <<= 1) {
                a  = fmaxf(a,  __shfl_xor(a,  o2));
                hh = fmaxf(hh, __shfl_xor(hh, o2));
            }
            if (ln == 0) {
                const int row = ti * 16 + q * 4 + reg;
                red[w * 64 + row]       = a;
                red[256 + w * 64 + row] = hh;
            }
        }
    if (l == 0) red[512 + w] = gmin;
    __syncthreads();
    if (t < 64) {
        const float a  = fmaxf(fmaxf(red[t], red[64 + t]),
                               fmaxf(red[128 + t], red[192 + t]));
        const float hh = fmaxf(fmaxf(red[256 + t], red[320 + t]),
                               fmaxf(red[384 + t], red[448 + t]));
        rmax_all[(size_t)hb * 1024 + r0 + t] = a * 0.015625f;
        rmax_hi [(size_t)hb * 1024 + r0 + t] = hh * 0.015625f;
    }
    if (t == 0)
        pmin[blk] = fminf(fminf(red[512], red[513]),
                          fminf(red[514], red[515])) * 0.015625f;
}

// Reduce raw min over head-0's blocks (blk 0..511).
__global__ void k_min(const float* __restrict__ pmin, float* __restrict__ m0) {
    __shared__ float s[4];
    const int t = threadIdx.x;
    float v = fminf(pmin[t], pmin[t + 256]);
#pragma unroll
    for (int off = 1; off < 64; off <<= 1) v = fminf(v, __shfl_xor(v, off));
    if ((t & 63) == 0) s[t >> 6] = v;
    __syncthreads();
    if (t == 0) m0[0] = fminf(fminf(s[0], s[1]), fminf(s[2], s[3]));
}

// alpha = act(rowmax_raw) + act(colmax_raw), m0 clip pre-activation (monotone).
__global__ void k_alpha(const float* __restrict__ rmax_all,
                        const float* __restrict__ rmax_hi,
                        const float* __restrict__ pcm,
                        const float* __restrict__ m0p,
                        float* __restrict__ alpha) {
    const int hb = blockIdx.x; // 0..63
    const float m0 = m0p[0];
    for (int it = 0; it < 4; ++it) {
        const int i = it * 256 + threadIdx.x;
        const float rraw = (i < 512) ? fmaxf(m0, rmax_hi[(size_t)hb * 1024 + i])
                                     : rmax_all[(size_t)hb * 1024 + i];
        float call = -INFINITY, chi = -INFINITY;
#pragma unroll
        for (int rb = 0; rb < 16; ++rb) {
            const float v = pcm[(size_t)(hb * 16 + rb) * 1024 + i];
            call = fmaxf(call, v);
            if (rb >= 8) chi = fmaxf(chi, v);
        }
        const float craw = (i < 512) ? fmaxf(m0, chi) : call;
        alpha[(size_t)hb * 1024 + i] = nonsat(rraw) + nonsat(craw);
    }
}

// softmax over each 512-segment + weighted pooling of the context.
__global__ __launch_bounds__(256)
void k_out(const float* __restrict__ alpha, const float* __restrict__ x1,
           const float* __restrict__ x2, float* __restrict__ out) {
    __shared__ float wv[512];
    __shared__ float sm[4], ss[4];
    const int blk = blockIdx.x;
    const int seg = blk & 1;
    const int hb  = blk >> 1;
    const int b   = hb & 31;
    const int t   = threadIdx.x;
    const float* ap = alpha + (size_t)hb * 1024 + seg * 512;
    const float a0 = ap[t], a1 = ap[t + 256];

    float m = fmaxf(a0, a1);
#pragma unroll
    for (int off = 1; off < 64; off <<= 1) m = fmaxf(m, __shfl_xor(m, off));
    if ((t & 63) == 0) sm[t >> 6] = m;
    __syncthreads();
    const float amax = fmaxf(fmaxf(sm[0], sm[1]), fmaxf(sm[2], sm[3]));

    const float e0 = __expf(a0 - amax), e1 = __expf(a1 - amax);
    wv[t] = e0; wv[t + 256] = e1;
    float s = e0 + e1;
#pragma unroll
    for (int off = 1; off < 64; off <<= 1) s += __shfl_xor(s, off);
    if ((t & 63) == 0) ss[t >> 6] = s;
    __syncthreads();
    const float inv = 1.0f / (ss[0] + ss[1] + ss[2] + ss[3]);

    float acc = 0.0f;
    if (seg == 0) {
        const float* xp = x1 + (size_t)b * 512 * 256 + t;
#pragma unroll 4
        for (int l = 0; l < 512; ++l) acc = fmaf(wv[l], xp[(size_t)l * 256], acc);
        out[blk * 256 + t] = acc * inv;
    } else {
        if (t < 192) {
            const float* xp = x2 + (size_t)b * 512 * 192 + t;
#pragma unroll 4
            for (int l = 0; l < 512; ++l) acc = fmaf(wv[l], xp[(size_t)l * 192], acc);
            out[blk * 256 + t] = acc * inv;
        } else {
            out[blk * 256 + t] = 0.0f;
        }
    }
}

extern "C" void kernel_launch(void* const* d_in, const int* in_sizes, int n_in,
                              void* d_out, int out_size, void* d_ws, size_t ws_size,
                              hipStream_t stream) {
    const float* x1 = (const float*)d_in[0];
    const float* x2 = (const float*)d_in[1];
    const float* U  = (const float*)d_in[2];
    float* out = (float*)d_out;
    char* wsb  = (char*)d_ws;

    h16*   MHp  = (h16*)(wsb + MH_OFF);
    h16*   MLp  = (h16*)(wsb + ML_OFF);
    h16*   UHt  = (h16*)(wsb + UHT_OFF);
    h16*   ULt  = (h16*)(wsb + ULT_OFF);
    float* rma  = (float*)(wsb + RMA_OFF);
    float* rmh  = (float*)(wsb + RMH_OFF);
    float* pcm  = (float*)(wsb + PCM_OFF);
    float* pmin = (float*)(wsb + PMIN_OFF);
    float* m0   = (float*)(wsb + M0_OFF);
    float* al   = (float*)(wsb + AL_OFF);

    hipLaunchKernelGGL(k_prep,  dim3(8320), dim3(256), 0, stream, x1, x2, U,
                       MHp, MLp, UHt, ULt);
    hipLaunchKernelGGL(k_main,  dim3(1024), dim3(256), 0, stream, MHp, MLp,
                       UHt, ULt, rma, rmh, pcm, pmin);
    hipLaunchKernelGGL(k_min,   dim3(1),    dim3(256), 0, stream, pmin, m0);
    hipLaunchKernelGGL(k_alpha, dim3(64),   dim3(256), 0, stream, rma, rmh, pcm, m0, al);
    hipLaunchKernelGGL(k_out,   dim3(128),  dim3(256), 0, stream, al, x1, x2, out);
}

// Round 3
// 307.561 us; speedup vs baseline: 2.5572x; 1.0256x over previous
//
#include <hip/hip_runtime.h>
#include <math.h>

typedef _Float16 h16;
typedef h16  h16x8 __attribute__((ext_vector_type(8)));
typedef h16  h16x4 __attribute__((ext_vector_type(4)));
typedef float f32x4 __attribute__((ext_vector_type(4)));

// ---------------- workspace layout (bytes) ----------------
// MH/ML : fp16 split of M [32 b][1024 j][256 d] (x2 zero-padded to 256)
// UHt/ULt: fp16 split of (U^T * 4) [2 h][256 d][256 c]   (*4 = 1/16 * 64 prescale)
// rmax_all/rmax_hi: [64 hb][1024] f32 ; pcm: [64 hb][16 rb][1024] f32
// m0key: ordered-int encoding of raw global min of head-0 K
#define MH_OFF   ((size_t)0)
#define ML_OFF   (MH_OFF + 16777216)
#define UHT_OFF  (ML_OFF + 16777216)
#define ULT_OFF  (UHT_OFF + 262144)
#define RMA_OFF  (ULT_OFF + 262144)
#define RMH_OFF  (RMA_OFF + 262144)
#define PCM_OFF  (RMH_OFF + 262144)
#define M0_OFF   (PCM_OFF + 4194304)

// Fully-converged Newton solve of y^3/3 + y = x (nonsat_activation limit).
// Strictly monotone -> commutes with max/min (applied post-reduction).
__device__ __forceinline__ float nonsat(float x) {
    float y = x;
#pragma unroll
    for (int i = 0; i < 24; ++i) {
        float y2 = y * y;
        y = fmaf(0.66666667f * y, y2, x) / (y2 + 1.0f);
    }
    return y;
}

// monotone float->int key (signed-int compare order == float order, no NaNs)
__device__ __forceinline__ int fkey(float f) {
    const int i = __float_as_int(f);
    return (i >= 0) ? i : (i ^ 0x7fffffff);
}
__device__ __forceinline__ float funkey(int k) {
    return __int_as_float((k >= 0) ? k : (k ^ 0x7fffffff));
}

// ---------------------------------------------------------------------------
// k_prep: fp16 hi/lo split of virtual M (x2 zero-padded) and of U^T*4.
// Also initializes the m0 atomic slot (ws is re-poisoned before every call).
// ---------------------------------------------------------------------------
__global__ void k_prep(const float* __restrict__ x1, const float* __restrict__ x2,
                       const float* __restrict__ U, h16* __restrict__ MH,
                       h16* __restrict__ ML, h16* __restrict__ UHt,
                       h16* __restrict__ ULt, int* __restrict__ m0key) {
    const int gid = blockIdx.x * 256 + threadIdx.x;
    if (blockIdx.x < 8192) {
        const int g  = gid;              // (b, j, d4): 32*1024*64 groups
        const int d4 = (g & 63) * 4;
        const int j  = (g >> 6) & 1023;
        const int b  = g >> 16;
        float v[4];
        if (j < 512) {
            const float* p = x1 + ((size_t)(b * 512 + j) * 256 + d4);
#pragma unroll
            for (int k = 0; k < 4; ++k) v[k] = p[k];
        } else {
            const float* p = x2 + (size_t)(b * 512 + (j - 512)) * 192;
#pragma unroll
            for (int k = 0; k < 4; ++k) {
                const int c = d4 + k;
                v[k] = (c < 192) ? p[c] : 0.0f;
            }
        }
        h16x4 hh, ll;
#pragma unroll
        for (int k = 0; k < 4; ++k) {
            const h16 hi = (h16)v[k];
            hh[k] = hi;
            ll[k] = (h16)(v[k] - (float)hi);
        }
        const size_t o = (size_t)g * 4;
        *(h16x4*)&MH[o] = hh;
        *(h16x4*)&ML[o] = ll;
    } else {
        const int g = gid - 8192 * 256;  // U^T: 2*256*64 groups
        if (g < 32768) {
            const int c4 = (g & 63) * 4;
            const int d  = (g >> 6) & 255;
            const int h  = g >> 14;
            h16x4 hh, ll;
#pragma unroll
            for (int k = 0; k < 4; ++k) {
                const float v = U[((size_t)h * 256 + c4 + k) * 256 + d] * 4.0f;
                const h16 hi = (h16)v;
                hh[k] = hi;
                ll[k] = (h16)(v - (float)hi);
            }
            const size_t o = ((size_t)h * 256 + d) * 256 + c4;
            *(h16x4*)&UHt[o] = hh;
            *(h16x4*)&ULt[o] = ll;
        } else if (g == 32768) {
            *m0key = 0x7fffffff;         // +max key
        }
    }
}

// ---------------------------------------------------------------------------
// k_main: block = (hb, 64-row slice). Phase A: P'[64][256] = M @ (U*4) via
// 3-term fp16-split MFMA, ALL fragments direct from global (no LDS, no
// barriers). Split P' hi/lo into swizzled LDS. One barrier. Phase B:
// K' = P'.M^T, A-frags from LDS (conflict-free XOR swizzle), B-frags direct
// from global, terms merged per k-chunk (MH loaded once for PH+PL terms).
// On-the-fly reductions; true K = K' * 2^-6. Only 2 barriers total.
// ---------------------------------------------------------------------------
__global__ __launch_bounds__(256, 2)
void k_main(const h16* __restrict__ MH, const h16* __restrict__ ML,
            const h16* __restrict__ UHt, const h16* __restrict__ ULt,
            float* __restrict__ rmax_all, float* __restrict__ rmax_hi,
            float* __restrict__ pcm, int* __restrict__ m0key) {
    __shared__ __align__(16) h16 sP[2][64 * 256];  // P hi/lo, [r][d] XOR-swizzled, 64 KB
    __shared__ float red[512 + 4];

    const int blk  = blockIdx.x;       // 1024
    const int rblk = blk & 15;
    const int hb   = blk >> 4;
    const int b    = hb & 31;
    const int h    = hb >> 5;
    const int r0   = rblk * 64;
    const int t    = threadIdx.x;
    const int w    = t >> 6;           // wave 0..3
    const int l    = t & 63;
    const int q    = l >> 4;           // quad -> k-offset q*8 / C-row q*4+reg
    const int ln   = l & 15;           // A row / B row / C col

    // ---------------- Phase A ----------------
    {
        f32x4 acc[4][4];
        const f32x4 z4 = {0.f, 0.f, 0.f, 0.f};
#pragma unroll
        for (int i = 0; i < 4; ++i)
#pragma unroll
            for (int j = 0; j < 4; ++j) acc[i][j] = z4;

        for (int kc = 0; kc < 8; ++kc) {
            const int c0 = kc * 32;
            h16x8 aH[4], aL[4], bH[4], bL[4];
#pragma unroll
            for (int ti = 0; ti < 4; ++ti) {
                const size_t off =
                    (size_t)(b * 1024 + r0 + ti * 16 + ln) * 256 + c0 + q * 8;
                aH[ti] = *(const h16x8*)&MH[off];
                aL[ti] = *(const h16x8*)&ML[off];
            }
#pragma unroll
            for (int tj = 0; tj < 4; ++tj) {
                const size_t off =
                    (size_t)(h * 256 + w * 64 + tj * 16 + ln) * 256 + c0 + q * 8;
                bH[tj] = *(const h16x8*)&UHt[off];
                bL[tj] = *(const h16x8*)&ULt[off];
            }
#pragma unroll
            for (int ti = 0; ti < 4; ++ti)
#pragma unroll
                for (int tj = 0; tj < 4; ++tj)
                    acc[ti][tj] = __builtin_amdgcn_mfma_f32_16x16x32_f16(
                        aH[ti], bH[tj], acc[ti][tj], 0, 0, 0);
#pragma unroll
            for (int ti = 0; ti < 4; ++ti)
#pragma unroll
                for (int tj = 0; tj < 4; ++tj)
                    acc[ti][tj] = __builtin_amdgcn_mfma_f32_16x16x32_f16(
                        aL[ti], bH[tj], acc[ti][tj], 0, 0, 0);
#pragma unroll
            for (int ti = 0; ti < 4; ++ti)
#pragma unroll
                for (int tj = 0; tj < 4; ++tj)
                    acc[ti][tj] = __builtin_amdgcn_mfma_f32_16x16x32_f16(
                        aH[ti], bL[tj], acc[ti][tj], 0, 0, 0);
        }
        // split-store P' into sP, granule-swizzled: gran' = gran ^ (r&7)
#pragma unroll
        for (int ti = 0; ti < 4; ++ti)
#pragma unroll
            for (int tj = 0; tj < 4; ++tj)
#pragma unroll
                for (int reg = 0; reg < 4; ++reg) {
                    const int r = ti * 16 + q * 4 + reg;   // C/D: row=q*4+reg
                    const int d = w * 64 + tj * 16 + ln;   //      col=ln
                    const float v = acc[ti][tj][reg];
                    const h16 hi = (h16)v;
                    const h16 lo = (h16)(v - (float)hi);
                    const int off = r * 256 + (((d >> 3) ^ (r & 7)) << 3) + (d & 7);
                    sP[0][off] = hi;
                    sP[1][off] = lo;
                }
    }
    __syncthreads();

    // ---------------- Phase B ----------------
    float gmin = INFINITY;

    for (int jt = 0; jt < 2; ++jt) {
        const int jbase = jt * 512 + w * 128;
        f32x4 acc[4][8];
        const f32x4 z4 = {0.f, 0.f, 0.f, 0.f};
#pragma unroll
        for (int i = 0; i < 4; ++i)
#pragma unroll
            for (int j = 0; j < 8; ++j) acc[i][j] = z4;

        for (int kc = 0; kc < 8; ++kc) {
            const int d0 = kc * 32;
            h16x8 aH[4], aL[4], bb[8];
#pragma unroll
            for (int ti = 0; ti < 4; ++ti) {
                const int r = ti * 16 + ln;
                const int g = (kc * 4 + q) ^ (r & 7);
                aH[ti] = *(const h16x8*)&sP[0][r * 256 + g * 8];
                aL[ti] = *(const h16x8*)&sP[1][r * 256 + g * 8];
            }
#pragma unroll
            for (int tj = 0; tj < 8; ++tj)
                bb[tj] = *(const h16x8*)&MH[
                    (size_t)(b * 1024 + jbase + tj * 16 + ln) * 256 + d0 + q * 8];
#pragma unroll
            for (int tj = 0; tj < 8; ++tj)
#pragma unroll
                for (int ti = 0; ti < 4; ++ti)
                    acc[ti][tj] = __builtin_amdgcn_mfma_f32_16x16x32_f16(
                        aH[ti], bb[tj], acc[ti][tj], 0, 0, 0);
#pragma unroll
            for (int tj = 0; tj < 8; ++tj)
#pragma unroll
                for (int ti = 0; ti < 4; ++ti)
                    acc[ti][tj] = __builtin_amdgcn_mfma_f32_16x16x32_f16(
                        aL[ti], bb[tj], acc[ti][tj], 0, 0, 0);
#pragma unroll
            for (int tj = 0; tj < 8; ++tj)
                bb[tj] = *(const h16x8*)&ML[
                    (size_t)(b * 1024 + jbase + tj * 16 + ln) * 256 + d0 + q * 8];
#pragma unroll
            for (int tj = 0; tj < 8; ++tj)
#pragma unroll
                for (int ti = 0; ti < 4; ++ti)
                    acc[ti][tj] = __builtin_amdgcn_mfma_f32_16x16x32_f16(
                        aH[ti], bb[tj], acc[ti][tj], 0, 0, 0);
        }

        // rowmax for this jt -> red[(jt*4+w)*64 + row] (lane ln==0 writes)
#pragma unroll
        for (int ti = 0; ti < 4; ++ti)
#pragma unroll
            for (int reg = 0; reg < 4; ++reg) {
                float m = acc[ti][0][reg];
#pragma unroll
                for (int tj = 1; tj < 8; ++tj) m = fmaxf(m, acc[ti][tj][reg]);
                m = fmaxf(m, __shfl_xor(m, 1));
                m = fmaxf(m, __shfl_xor(m, 2));
                m = fmaxf(m, __shfl_xor(m, 4));
                m = fmaxf(m, __shfl_xor(m, 8));
                if (ln == 0)
                    red[(jt * 4 + w) * 64 + ti * 16 + q * 4 + reg] = m;
            }
        // colmax over this block's 64 rows -> pcm (quads combined via shfl)
#pragma unroll
        for (int tj = 0; tj < 8; ++tj) {
            float m = -INFINITY;
#pragma unroll
            for (int ti = 0; ti < 4; ++ti)
#pragma unroll
                for (int reg = 0; reg < 4; ++reg) m = fmaxf(m, acc[ti][tj][reg]);
            m = fmaxf(m, __shfl_xor(m, 16));
            m = fmaxf(m, __shfl_xor(m, 32));
            if (q == 0)
                pcm[(size_t)(hb * 16 + rblk) * 1024 + jbase + tj * 16 + ln] =
                    m * 0.015625f;
        }
        // raw min
#pragma unroll
        for (int ti = 0; ti < 4; ++ti)
#pragma unroll
            for (int tj = 0; tj < 8; ++tj)
#pragma unroll
                for (int reg = 0; reg < 4; ++reg)
                    gmin = fminf(gmin, acc[ti][tj][reg]);
    }

#pragma unroll
    for (int off = 1; off < 64; off <<= 1) gmin = fminf(gmin, __shfl_xor(gmin, off));
    if (l == 0) red[512 + w] = gmin;
    __syncthreads();

    if (t < 64) {
        float a = -INFINITY, hh = -INFINITY;
#pragma unroll
        for (int w2 = 0; w2 < 4; ++w2) {
            a  = fmaxf(a,  red[w2 * 64 + t]);          // jt0
            const float v1 = red[(4 + w2) * 64 + t];   // jt1
            a  = fmaxf(a, v1);
            hh = fmaxf(hh, v1);
        }
        rmax_all[(size_t)hb * 1024 + r0 + t] = a  * 0.015625f;
        rmax_hi [(size_t)hb * 1024 + r0 + t] = hh * 0.015625f;
    }
    if (t == 0 && hb < 32) {   // head 0 only feeds mask_add
        const float g4 = fminf(fminf(red[512], red[513]),
                               fminf(red[514], red[515])) * 0.015625f;
        atomicMin(m0key, fkey(g4));
    }
}

// ---------------------------------------------------------------------------
// k_fin: fused alpha (activation applied post-reduction) + softmax + pooling.
// block = hb*2 + seg, 128 blocks x 256 threads.
// ---------------------------------------------------------------------------
__global__ __launch_bounds__(256)
void k_fin(const float* __restrict__ rmax_all, const float* __restrict__ rmax_hi,
           const float* __restrict__ pcm, const int* __restrict__ m0key,
           const float* __restrict__ x1, const float* __restrict__ x2,
           float* __restrict__ out) {
    __shared__ float wv[512];
    __shared__ float sm[4], ss[4];
    const int blk = blockIdx.x;
    const int seg = blk & 1;
    const int hb  = blk >> 1;
    const int b   = hb & 31;
    const int t   = threadIdx.x;
    const float m0 = funkey(*m0key);

    float a2[2];
#pragma unroll
    for (int half = 0; half < 2; ++half) {
        const int i = seg * 512 + half * 256 + t;
        float rraw;
        if (seg == 0) rraw = fmaxf(m0, rmax_hi[(size_t)hb * 1024 + i]);
        else          rraw = rmax_all[(size_t)hb * 1024 + i];
        float call = -INFINITY, chi = -INFINITY;
#pragma unroll
        for (int rb = 0; rb < 16; ++rb) {
            const float v = pcm[(size_t)(hb * 16 + rb) * 1024 + i];
            call = fmaxf(call, v);
            if (rb >= 8) chi = fmaxf(chi, v);
        }
        const float craw = (seg == 0) ? fmaxf(m0, chi) : call;
        a2[half] = nonsat(rraw) + nonsat(craw);
    }
    const float a0 = a2[0], a1 = a2[1];

    float m = fmaxf(a0, a1);
#pragma unroll
    for (int off = 1; off < 64; off <<= 1) m = fmaxf(m, __shfl_xor(m, off));
    if ((t & 63) == 0) sm[t >> 6] = m;
    __syncthreads();
    const float amax = fmaxf(fmaxf(sm[0], sm[1]), fmaxf(sm[2], sm[3]));

    const float e0 = __expf(a0 - amax), e1 = __expf(a1 - amax);
    wv[t] = e0; wv[t + 256] = e1;
    float s = e0 + e1;
#pragma unroll
    for (int off = 1; off < 64; off <<= 1) s += __shfl_xor(s, off);
    if ((t & 63) == 0) ss[t >> 6] = s;
    __syncthreads();
    const float inv = 1.0f / (ss[0] + ss[1] + ss[2] + ss[3]);

    float acc = 0.0f;
    if (seg == 0) {
        const float* xp = x1 + (size_t)b * 512 * 256 + t;
#pragma unroll 4
        for (int l = 0; l < 512; ++l) acc = fmaf(wv[l], xp[(size_t)l * 256], acc);
        out[blk * 256 + t] = acc * inv;
    } else {
        if (t < 192) {
            const float* xp = x2 + (size_t)b * 512 * 192 + t;
#pragma unroll 4
            for (int l = 0; l < 512; ++l) acc = fmaf(wv[l], xp[(size_t)l * 192], acc);
            out[blk * 256 + t] = acc * inv;
        } else {
            out[blk * 256 + t] = 0.0f;   // padded channels: exact zero
        }
    }
}

extern "C" void kernel_launch(void* const* d_in, const int* in_sizes, int n_in,
                              void* d_out, int out_size, void* d_ws, size_t ws_size,
                              hipStream_t stream) {
    const float* x1 = (const float*)d_in[0];
    const float* x2 = (const float*)d_in[1];
    const float* U  = (const float*)d_in[2];
    float* out = (float*)d_out;
    char* wsb  = (char*)d_ws;

    h16*   MHp  = (h16*)(wsb + MH_OFF);
    h16*   MLp  = (h16*)(wsb + ML_OFF);
    h16*   UHt  = (h16*)(wsb + UHT_OFF);
    h16*   ULt  = (h16*)(wsb + ULT_OFF);
    float* rma  = (float*)(wsb + RMA_OFF);
    float* rmh  = (float*)(wsb + RMH_OFF);
    float* pcm  = (float*)(wsb + PCM_OFF);
    int*   m0k  = (int*)(wsb + M0_OFF);

    hipLaunchKernelGGL(k_prep, dim3(8321), dim3(256), 0, stream, x1, x2, U,
                       MHp, MLp, UHt, ULt, m0k);
    hipLaunchKernelGGL(k_main, dim3(1024), dim3(256), 0, stream, MHp, MLp,
                       UHt, ULt, rma, rmh, pcm, m0k);
    hipLaunchKernelGGL(k_fin,  dim3(128),  dim3(256), 0, stream, rma, rmh,
                       pcm, m0k, x1, x2, out);
}

// Round 4
// 296.902 us; speedup vs baseline: 2.6490x; 1.0359x over previous
//
#include <hip/hip_runtime.h>
#include <math.h>

typedef _Float16 h16;
typedef h16  h16x8 __attribute__((ext_vector_type(8)));
typedef h16  h16x4 __attribute__((ext_vector_type(4)));
typedef float f32x4 __attribute__((ext_vector_type(4)));

// ---------------- workspace layout (bytes) ----------------
// MH/ML : fp16 split of M [32 b][1024 j][256 d] (x2 zero-padded to 256)
// UHt/ULt: fp16 split of (U^T * 4) [2 h][256 d][256 c]   (*4 = 1/16 * 64 prescale)
// rmax_all/rmax_hi: [64 hb][1024] f32 ; pcm: [64 hb][16 rb][1024] f32
// m0key: ordered-int encoding of raw global min of head-0 K
#define MH_OFF   ((size_t)0)
#define ML_OFF   (MH_OFF + 16777216)
#define UHT_OFF  (ML_OFF + 16777216)
#define ULT_OFF  (UHT_OFF + 262144)
#define RMA_OFF  (ULT_OFF + 262144)
#define RMH_OFF  (RMA_OFF + 262144)
#define PCM_OFF  (RMH_OFF + 262144)
#define M0_OFF   (PCM_OFF + 4194304)

// Fully-converged Newton solve of y^3/3 + y = x (nonsat_activation limit).
// Strictly monotone -> commutes with max/min (applied post-reduction).
__device__ __forceinline__ float nonsat(float x) {
    float y = x;
#pragma unroll
    for (int i = 0; i < 24; ++i) {
        float y2 = y * y;
        y = fmaf(0.66666667f * y, y2, x) / (y2 + 1.0f);
    }
    return y;
}

// monotone float->int key (signed-int compare order == float order, no NaNs)
__device__ __forceinline__ int fkey(float f) {
    const int i = __float_as_int(f);
    return (i >= 0) ? i : (i ^ 0x7fffffff);
}
__device__ __forceinline__ float funkey(int k) {
    return __int_as_float((k >= 0) ? k : (k ^ 0x7fffffff));
}

// ---------------------------------------------------------------------------
// k_prep: fp16 hi/lo split of virtual M (x2 zero-padded) and of U^T*4.
// Also initializes the m0 atomic slot (ws is re-poisoned before every call).
// ---------------------------------------------------------------------------
__global__ void k_prep(const float* __restrict__ x1, const float* __restrict__ x2,
                       const float* __restrict__ U, h16* __restrict__ MH,
                       h16* __restrict__ ML, h16* __restrict__ UHt,
                       h16* __restrict__ ULt, int* __restrict__ m0key) {
    const int gid = blockIdx.x * 256 + threadIdx.x;
    if (blockIdx.x < 8192) {
        const int g  = gid;              // (b, j, d4): 32*1024*64 groups
        const int d4 = (g & 63) * 4;
        const int j  = (g >> 6) & 1023;
        const int b  = g >> 16;
        float v[4];
        if (j < 512) {
            const float* p = x1 + ((size_t)(b * 512 + j) * 256 + d4);
#pragma unroll
            for (int k = 0; k < 4; ++k) v[k] = p[k];
        } else {
            const float* p = x2 + (size_t)(b * 512 + (j - 512)) * 192;
#pragma unroll
            for (int k = 0; k < 4; ++k) {
                const int c = d4 + k;
                v[k] = (c < 192) ? p[c] : 0.0f;
            }
        }
        h16x4 hh, ll;
#pragma unroll
        for (int k = 0; k < 4; ++k) {
            const h16 hi = (h16)v[k];
            hh[k] = hi;
            ll[k] = (h16)(v[k] - (float)hi);
        }
        const size_t o = (size_t)g * 4;
        *(h16x4*)&MH[o] = hh;
        *(h16x4*)&ML[o] = ll;
    } else {
        const int g = gid - 8192 * 256;  // U^T: 2*256*64 groups
        if (g < 32768) {
            const int c4 = (g & 63) * 4;
            const int d  = (g >> 6) & 255;
            const int h  = g >> 14;
            h16x4 hh, ll;
#pragma unroll
            for (int k = 0; k < 4; ++k) {
                const float v = U[((size_t)h * 256 + c4 + k) * 256 + d] * 4.0f;
                const h16 hi = (h16)v;
                hh[k] = hi;
                ll[k] = (h16)(v - (float)hi);
            }
            const size_t o = ((size_t)h * 256 + d) * 256 + c4;
            *(h16x4*)&UHt[o] = hh;
            *(h16x4*)&ULt[o] = ll;
        } else if (g == 32768) {
            *m0key = 0x7fffffff;         // +max key
        }
    }
}

// ---------------------------------------------------------------------------
// k_main: block = (hb, 64-row slice). Phase A: P'[64][256] = M @ (U*4) via
// 3-term fp16-split MFMA, ALL fragments direct from global. Split P' hi/lo
// into swizzled LDS. One barrier. Phase B: K' = P'.M^T, A-frags from LDS
// (conflict-free XOR swizzle), B-frags direct from global.
// XCD-affine block swizzle: all work for batch b runs on XCD b%8, so the
// B-operand stream (MH/ML[b], ~2 MB) stays L2-resident per XCD instead of
// being re-fetched by all 8 XCDs (R3: FETCH_SIZE 384 MB vs 33 MB unique).
// On-the-fly reductions; true K = K' * 2^-6. 2 barriers total.
// ---------------------------------------------------------------------------
__global__ __launch_bounds__(256, 2)
void k_main(const h16* __restrict__ MH, const h16* __restrict__ ML,
            const h16* __restrict__ UHt, const h16* __restrict__ ULt,
            float* __restrict__ rmax_all, float* __restrict__ rmax_hi,
            float* __restrict__ pcm, int* __restrict__ m0key) {
    __shared__ __align__(16) h16 sP[2][64 * 256];  // P hi/lo, [r][d] XOR-swizzled, 64 KB
    __shared__ float red[512 + 4];

    // XCD-affine swizzle (assumes round-robin blk%8 -> XCD; bijective either way)
    const int n    = blockIdx.x;       // 1024
    const int x    = n & 7;            // presumed XCD
    const int s    = n >> 3;           // 0..127 slot on this XCD
    const int b    = x + 8 * (s >> 5); // batch: 4 per XCD, contiguous in time
    const int h    = (s >> 4) & 1;
    const int rblk = s & 15;
    const int hb   = h * 32 + b;
    const int r0   = rblk * 64;
    const int t    = threadIdx.x;
    const int w    = t >> 6;           // wave 0..3
    const int l    = t & 63;
    const int q    = l >> 4;           // quad -> k-offset q*8 / C-row q*4+reg
    const int ln   = l & 15;           // A row / B row / C col

    // ---------------- Phase A ----------------
    {
        f32x4 acc[4][4];
        const f32x4 z4 = {0.f, 0.f, 0.f, 0.f};
#pragma unroll
        for (int i = 0; i < 4; ++i)
#pragma unroll
            for (int j = 0; j < 4; ++j) acc[i][j] = z4;

        for (int kc = 0; kc < 8; ++kc) {
            const int c0 = kc * 32;
            h16x8 aH[4], aL[4], bH[4], bL[4];
#pragma unroll
            for (int ti = 0; ti < 4; ++ti) {
                const size_t off =
                    (size_t)(b * 1024 + r0 + ti * 16 + ln) * 256 + c0 + q * 8;
                aH[ti] = *(const h16x8*)&MH[off];
                aL[ti] = *(const h16x8*)&ML[off];
            }
#pragma unroll
            for (int tj = 0; tj < 4; ++tj) {
                const size_t off =
                    (size_t)(h * 256 + w * 64 + tj * 16 + ln) * 256 + c0 + q * 8;
                bH[tj] = *(const h16x8*)&UHt[off];
                bL[tj] = *(const h16x8*)&ULt[off];
            }
#pragma unroll
            for (int ti = 0; ti < 4; ++ti)
#pragma unroll
                for (int tj = 0; tj < 4; ++tj)
                    acc[ti][tj] = __builtin_amdgcn_mfma_f32_16x16x32_f16(
                        aH[ti], bH[tj], acc[ti][tj], 0, 0, 0);
#pragma unroll
            for (int ti = 0; ti < 4; ++ti)
#pragma unroll
                for (int tj = 0; tj < 4; ++tj)
                    acc[ti][tj] = __builtin_amdgcn_mfma_f32_16x16x32_f16(
                        aL[ti], bH[tj], acc[ti][tj], 0, 0, 0);
#pragma unroll
            for (int ti = 0; ti < 4; ++ti)
#pragma unroll
                for (int tj = 0; tj < 4; ++tj)
                    acc[ti][tj] = __builtin_amdgcn_mfma_f32_16x16x32_f16(
                        aH[ti], bL[tj], acc[ti][tj], 0, 0, 0);
        }
        // split-store P' into sP, granule-swizzled: gran' = gran ^ (r&7)
#pragma unroll
        for (int ti = 0; ti < 4; ++ti)
#pragma unroll
            for (int tj = 0; tj < 4; ++tj)
#pragma unroll
                for (int reg = 0; reg < 4; ++reg) {
                    const int r = ti * 16 + q * 4 + reg;   // C/D: row=q*4+reg
                    const int d = w * 64 + tj * 16 + ln;   //      col=ln
                    const float v = acc[ti][tj][reg];
                    const h16 hi = (h16)v;
                    const h16 lo = (h16)(v - (float)hi);
                    const int off = r * 256 + (((d >> 3) ^ (r & 7)) << 3) + (d & 7);
                    sP[0][off] = hi;
                    sP[1][off] = lo;
                }
    }
    __syncthreads();

    // ---------------- Phase B ----------------
    float gmin = INFINITY;

    for (int jt = 0; jt < 2; ++jt) {
        const int jbase = jt * 512 + w * 128;
        f32x4 acc[4][8];
        const f32x4 z4 = {0.f, 0.f, 0.f, 0.f};
#pragma unroll
        for (int i = 0; i < 4; ++i)
#pragma unroll
            for (int j = 0; j < 8; ++j) acc[i][j] = z4;

        for (int kc = 0; kc < 8; ++kc) {
            const int d0 = kc * 32;
            h16x8 aH[4], aL[4], bb[8];
#pragma unroll
            for (int ti = 0; ti < 4; ++ti) {
                const int r = ti * 16 + ln;
                const int g = (kc * 4 + q) ^ (r & 7);
                aH[ti] = *(const h16x8*)&sP[0][r * 256 + g * 8];
                aL[ti] = *(const h16x8*)&sP[1][r * 256 + g * 8];
            }
#pragma unroll
            for (int tj = 0; tj < 8; ++tj)
                bb[tj] = *(const h16x8*)&MH[
                    (size_t)(b * 1024 + jbase + tj * 16 + ln) * 256 + d0 + q * 8];
#pragma unroll
            for (int tj = 0; tj < 8; ++tj)
#pragma unroll
                for (int ti = 0; ti < 4; ++ti)
                    acc[ti][tj] = __builtin_amdgcn_mfma_f32_16x16x32_f16(
                        aH[ti], bb[tj], acc[ti][tj], 0, 0, 0);
#pragma unroll
            for (int tj = 0; tj < 8; ++tj)
#pragma unroll
                for (int ti = 0; ti < 4; ++ti)
                    acc[ti][tj] = __builtin_amdgcn_mfma_f32_16x16x32_f16(
                        aL[ti], bb[tj], acc[ti][tj], 0, 0, 0);
#pragma unroll
            for (int tj = 0; tj < 8; ++tj)
                bb[tj] = *(const h16x8*)&ML[
                    (size_t)(b * 1024 + jbase + tj * 16 + ln) * 256 + d0 + q * 8];
#pragma unroll
            for (int tj = 0; tj < 8; ++tj)
#pragma unroll
                for (int ti = 0; ti < 4; ++ti)
                    acc[ti][tj] = __builtin_amdgcn_mfma_f32_16x16x32_f16(
                        aH[ti], bb[tj], acc[ti][tj], 0, 0, 0);
        }

        // rowmax for this jt -> red[(jt*4+w)*64 + row] (lane ln==0 writes)
#pragma unroll
        for (int ti = 0; ti < 4; ++ti)
#pragma unroll
            for (int reg = 0; reg < 4; ++reg) {
                float m = acc[ti][0][reg];
#pragma unroll
                for (int tj = 1; tj < 8; ++tj) m = fmaxf(m, acc[ti][tj][reg]);
                m = fmaxf(m, __shfl_xor(m, 1));
                m = fmaxf(m, __shfl_xor(m, 2));
                m = fmaxf(m, __shfl_xor(m, 4));
                m = fmaxf(m, __shfl_xor(m, 8));
                if (ln == 0)
                    red[(jt * 4 + w) * 64 + ti * 16 + q * 4 + reg] = m;
            }
        // colmax over this block's 64 rows -> pcm (quads combined via shfl)
#pragma unroll
        for (int tj = 0; tj < 8; ++tj) {
            float m = -INFINITY;
#pragma unroll
            for (int ti = 0; ti < 4; ++ti)
#pragma unroll
                for (int reg = 0; reg < 4; ++reg) m = fmaxf(m, acc[ti][tj][reg]);
            m = fmaxf(m, __shfl_xor(m, 16));
            m = fmaxf(m, __shfl_xor(m, 32));
            if (q == 0)
                pcm[(size_t)(hb * 16 + rblk) * 1024 + jbase + tj * 16 + ln] =
                    m * 0.015625f;
        }
        // raw min
#pragma unroll
        for (int ti = 0; ti < 4; ++ti)
#pragma unroll
            for (int tj = 0; tj < 8; ++tj)
#pragma unroll
                for (int reg = 0; reg < 4; ++reg)
                    gmin = fminf(gmin, acc[ti][tj][reg]);
    }

#pragma unroll
    for (int off = 1; off < 64; off <<= 1) gmin = fminf(gmin, __shfl_xor(gmin, off));
    if (l == 0) red[512 + w] = gmin;
    __syncthreads();

    if (t < 64) {
        float a = -INFINITY, hh = -INFINITY;
#pragma unroll
        for (int w2 = 0; w2 < 4; ++w2) {
            a  = fmaxf(a,  red[w2 * 64 + t]);          // jt0
            const float v1 = red[(4 + w2) * 64 + t];   // jt1
            a  = fmaxf(a, v1);
            hh = fmaxf(hh, v1);
        }
        rmax_all[(size_t)hb * 1024 + r0 + t] = a  * 0.015625f;
        rmax_hi [(size_t)hb * 1024 + r0 + t] = hh * 0.015625f;
    }
    if (t == 0 && hb < 32) {   // head 0 only feeds mask_add
        const float g4 = fminf(fminf(red[512], red[513]),
                               fminf(red[514], red[515])) * 0.015625f;
        atomicMin(m0key, fkey(g4));
    }
}

// ---------------------------------------------------------------------------
// k_fin: fused alpha (activation applied post-reduction) + softmax + pooling.
// block = hb*2 + seg, 128 blocks x 256 threads.
// ---------------------------------------------------------------------------
__global__ __launch_bounds__(256)
void k_fin(const float* __restrict__ rmax_all, const float* __restrict__ rmax_hi,
           const float* __restrict__ pcm, const int* __restrict__ m0key,
           const float* __restrict__ x1, const float* __restrict__ x2,
           float* __restrict__ out) {
    __shared__ float wv[512];
    __shared__ float sm[4], ss[4];
    const int blk = blockIdx.x;
    const int seg = blk & 1;
    const int hb  = blk >> 1;
    const int b   = hb & 31;
    const int t   = threadIdx.x;
    const float m0 = funkey(*m0key);

    float a2[2];
#pragma unroll
    for (int half = 0; half < 2; ++half) {
        const int i = seg * 512 + half * 256 + t;
        float rraw;
        if (seg == 0) rraw = fmaxf(m0, rmax_hi[(size_t)hb * 1024 + i]);
        else          rraw = rmax_all[(size_t)hb * 1024 + i];
        float call = -INFINITY, chi = -INFINITY;
#pragma unroll
        for (int rb = 0; rb < 16; ++rb) {
            const float v = pcm[(size_t)(hb * 16 + rb) * 1024 + i];
            call = fmaxf(call, v);
            if (rb >= 8) chi = fmaxf(chi, v);
        }
        const float craw = (seg == 0) ? fmaxf(m0, chi) : call;
        a2[half] = nonsat(rraw) + nonsat(craw);
    }
    const float a0 = a2[0], a1 = a2[1];

    float m = fmaxf(a0, a1);
#pragma unroll
    for (int off = 1; off < 64; off <<= 1) m = fmaxf(m, __shfl_xor(m, off));
    if ((t & 63) == 0) sm[t >> 6] = m;
    __syncthreads();
    const float amax = fmaxf(fmaxf(sm[0], sm[1]), fmaxf(sm[2], sm[3]));

    const float e0 = __expf(a0 - amax), e1 = __expf(a1 - amax);
    wv[t] = e0; wv[t + 256] = e1;
    float s = e0 + e1;
#pragma unroll
    for (int off = 1; off < 64; off <<= 1) s += __shfl_xor(s, off);
    if ((t & 63) == 0) ss[t >> 6] = s;
    __syncthreads();
    const float inv = 1.0f / (ss[0] + ss[1] + ss[2] + ss[3]);

    float acc = 0.0f;
    if (seg == 0) {
        const float* xp = x1 + (size_t)b * 512 * 256 + t;
#pragma unroll 4
        for (int l = 0; l < 512; ++l) acc = fmaf(wv[l], xp[(size_t)l * 256], acc);
        out[blk * 256 + t] = acc * inv;
    } else {
        if (t < 192) {
            const float* xp = x2 + (size_t)b * 512 * 192 + t;
#pragma unroll 4
            for (int l = 0; l < 512; ++l) acc = fmaf(wv[l], xp[(size_t)l * 192], acc);
            out[blk * 256 + t] = acc * inv;
        } else {
            out[blk * 256 + t] = 0.0f;   // padded channels: exact zero
        }
    }
}

extern "C" void kernel_launch(void* const* d_in, const int* in_sizes, int n_in,
                              void* d_out, int out_size, void* d_ws, size_t ws_size,
                              hipStream_t stream) {
    const float* x1 = (const float*)d_in[0];
    const float* x2 = (const float*)d_in[1];
    const float* U  = (const float*)d_in[2];
    float* out = (float*)d_out;
    char* wsb  = (char*)d_ws;

    h16*   MHp  = (h16*)(wsb + MH_OFF);
    h16*   MLp  = (h16*)(wsb + ML_OFF);
    h16*   UHt  = (h16*)(wsb + UHT_OFF);
    h16*   ULt  = (h16*)(wsb + ULT_OFF);
    float* rma  = (float*)(wsb + RMA_OFF);
    float* rmh  = (float*)(wsb + RMH_OFF);
    float* pcm  = (float*)(wsb + PCM_OFF);
    int*   m0k  = (int*)(wsb + M0_OFF);

    hipLaunchKernelGGL(k_prep, dim3(8321), dim3(256), 0, stream, x1, x2, U,
                       MHp, MLp, UHt, ULt, m0k);
    hipLaunchKernelGGL(k_main, dim3(1024), dim3(256), 0, stream, MHp, MLp,
                       UHt, ULt, rma, rmh, pcm, m0k);
    hipLaunchKernelGGL(k_fin,  dim3(128),  dim3(256), 0, stream, rma, rmh,
                       pcm, m0k, x1, x2, out);
}